// Round 3
// baseline (26309.729 us; speedup 1.0000x reference)
//
#include <hip/hip_runtime.h>

// Problem constants
#define B_    64
#define T_    512
#define KDIM  1024
#define HID_  1024

// R15 geometry: 128x64 block tile, 8x4 per-thread, BK=16 thin slices.
#define BM 128    // t-chunk per block iteration (4 chunks)
#define BN 64     // h-tile per block
#define BK 16     // one numpy 16-k block per slice
#define LDA 20    // padded LDS row: 16 + 4 floats (80 B, 16B-aligned rows)
#define NSL 256   // total slices = (T_/BM)*(KDIM/BK) = 4*64
#define SPC 64    // slices per chunk = KDIM/BK
#define ABOFF 2560  // B region offset within a buffer (128*20 floats)
#define BUFSZ 3840  // per-buffer floats: A 128x20 + B 64x20
#define ISMLD 65    // Ism [32][65] = 2080 f, aliased inside AB1 (3840 f)
#define BSHOFF 7680
// total smem floats = 7680 + 64 = 7744 (30976 B -> 5 blocks/CU by LDS)

// f32 correctly rounded from python float math.exp(-1.0/20.0)
#define ALPHA_F 0.95122942450071400909f

typedef float v4f __attribute__((ext_vector_type(4)));
typedef float v2f __attribute__((ext_vector_type(2)));

// Bit-faithful replication of the harness numpy f32 reference: per output
// element 4 f32 accumulator lanes (lane l sums k = l mod 4), 16-k blocks
// ascending (slices ascending), q descending within block, mul/add separately
// rounded (no FMA), hadd tree (l0+l1)+(l2+l3), one f32 bias add; f32 scan.
// Chain byte-identical to R6..R14 (all PASSED).
//
// R15 vs R12 (1.505 ms): R12 is LDS-ISSUE-bound, not VALU- or LDS-byte-bound:
// per CU-slice 16 waves x 64 ds_read_b128 x ~12cy = 12288 cy vs 8192 cy VALU
// -> busy 8192/12288 = 67% ~ measured 72%. (R13 proved bytes don't matter:
// half the bytes at 2x instrs = same cycles, and it regressed on occupancy.
// R14's launch_bounds(256,5) register squeeze spilled acc to scratch: 21 GB
// scratch writes.) Balance law per q-step, r x c per-thread tile: LDS-bound
// iff 3(r+c) > rc. 4x4 -> 1.5x; 8x4 -> 1.125x. R15: BM=128, 8x4 tile, BK=16.
// LDS 30.7 KB (5 blocks by LDS), regs ~115 with launch_bounds(256,4) (the
// budget R12/R13 compiled cleanly at) -> 4 blocks x 4 waves = 16 waves/CU,
// same occupancy as R12 with 25% less LDS-pipe demand.
__global__ __launch_bounds__(256, 4) void snn_np_wide(
    const float* __restrict__ x,     // [B,T,K] f32
    const float* __restrict__ W,     // [H,K] f32
    const float* __restrict__ bias,  // [H] f32
    float* __restrict__ spikes,      // [B,T,H] f32 out
    float* __restrict__ memf)        // [B,H] f32 out
{
#pragma clang fp contract(off)       // numpy SSE path has no FMA: mul+add only
    __shared__ float smem[7744];     // 30976 B total
    float* const AB0 = smem;             // A @0, B @2560
    float* const AB1 = smem + BUFSZ;     // A, B buffer 1
    float* const Ism = AB1;              // [32][65] — aliases AB1 (disjoint phases)
    float* const bsh = smem + BSHOFF;    // [64]

    const int tid = threadIdx.x;
    const int bb  = blockIdx.x;          // batch index
    const int h0  = blockIdx.y * BN;     // h tile origin

    const int tx = tid & 15;             // h micro-index (4 cols, stride 16)
    const int ty = tid >> 4;             // t micro-index (8 rows, stride 16)

    const int srA = tid >> 1;            // A staging row 0..127
    const int scA = (tid & 1) << 3;      // A staging col 0 or 8 (two float4s)
    const int srB = tid >> 2;            // B staging row 0..63
    const int scB = (tid & 3) << 2;      // B staging col 0,4,8,12

    const float* xb = x + (size_t)bb * T_ * KDIM;
    const float* Wb = W + (size_t)h0 * KDIM;

    if (tid < BN) bsh[tid] = bias[h0 + tid];

    float mem = 0.0f;                    // threads 0..63 carry h = h0+tid

    // ---- prologue: slice 0 -> AB0; slice 1 -> regs ----
    float4 pa0, pa1, pw;
    pa0 = *(const float4*)&xb[(size_t)srA * KDIM + scA];
    pa1 = *(const float4*)&xb[(size_t)srA * KDIM + scA + 4];
    pw  = *(const float4*)&Wb[(size_t)srB * KDIM + scB];
    *(float4*)&AB0[srA * LDA + scA]         = pa0;
    *(float4*)&AB0[srA * LDA + scA + 4]     = pa1;
    *(float4*)&AB0[ABOFF + srB * LDA + scB] = pw;
    pa0 = *(const float4*)&xb[(size_t)srA * KDIM + 16 + scA];
    pa1 = *(const float4*)&xb[(size_t)srA * KDIM + 16 + scA + 4];
    pw  = *(const float4*)&Wb[(size_t)srB * KDIM + 16 + scB];
    __syncthreads();                     // AB0 + bsh visible

    for (int c = 0; c < T_ / BM; ++c) {
        // numpy 4-lane accumulators, lane-paired: p01 = lanes {0,1}, p23 = {2,3}
        v2f p01[8][4], p23[8][4];
#pragma unroll
        for (int j = 0; j < 8; ++j)
#pragma unroll
            for (int i = 0; i < 4; ++i) {
                p01[j][i] = (v2f)(0.0f);
                p23[j][i] = (v2f)(0.0f);
            }

        for (int s = 0; s < SPC; ++s) {
            const int g = c * SPC + s;
            float* const cb = (g & 1) ? AB1 : AB0;   // compute buffer (slice g)
            float* const nb = (g & 1) ? AB0 : AB1;   // commit target (slice g+1)

            // 1) commit regs (slice g+1) into nb — overlapped with compute;
            //    nb's old readers finished before the previous barrier.
            if (g + 1 < NSL) {
                *(float4*)&nb[srA * LDA + scA]         = pa0;
                *(float4*)&nb[srA * LDA + scA + 4]     = pa1;
                *(float4*)&nb[ABOFF + srB * LDA + scB] = pw;
            }
            // 2) issue slice g+2 loads; a whole compute phase to land.
            if (g + 2 < NSL) {
                const int gs  = g + 2;
                const int nt0 = (gs >> 6) * BM;
                const int nk  = (gs & 63) << 4;
                pa0 = *(const float4*)&xb[(size_t)(nt0 + srA) * KDIM + nk + scA];
                pa1 = *(const float4*)&xb[(size_t)(nt0 + srA) * KDIM + nk + scA + 4];
                pw  = *(const float4*)&Wb[(size_t)srB * KDIM + nk + scB];
            }
            // 3) compute slice g: one numpy 16-k block; q=3..0 —
            // per-lane acc += a[4q+l]*b[4q+l], mul then add: bitwise equal to
            // numpy's chained a0b0+(a1b1+(a2b2+(a3b3+acc)))
#pragma unroll
            for (int q = 3; q >= 0; --q) {
                const int qc = q << 2;
                v2f a01[8], a23[8], b01[4], b23[4];
#pragma unroll
                for (int j = 0; j < 8; ++j) {
                    const v4f a = *(const v4f*)&cb[(ty + 16 * j) * LDA + qc];
                    a01[j] = a.xy; a23[j] = a.zw;
                }
#pragma unroll
                for (int i = 0; i < 4; ++i) {
                    const v4f b = *(const v4f*)&cb[ABOFF + (tx + 16 * i) * LDA + qc];
                    b01[i] = b.xy; b23[i] = b.zw;
                }
#pragma unroll
                for (int j = 0; j < 8; ++j)
#pragma unroll
                    for (int i = 0; i < 4; ++i) {
                        const v2f m01 = a01[j] * b01[i];   // packed rounded muls
                        const v2f m23 = a23[j] * b23[i];
                        p01[j][i] = p01[j][i] + m01;       // packed rounded adds
                        p23[j][i] = p23[j][i] + m23;
                    }
            }
            __syncthreads();   // slice g reads done; slice g+1 commit visible
        }

        // epilogue in four 32-row halves (Ism = [32][65] aliases AB1).
        // Chunk-final slice (g = c*64+63) is odd: computed from AB1, committed
        // next-chunk slice 0 into AB0 — AB1 is free; AB0 survives the scans.
        // Next chunk's first commit targets AB1, after the last scan barrier.
#pragma unroll
        for (int half = 0; half < 4; ++half) {
#pragma unroll
            for (int j = 0; j < 2; ++j) {
                const int jj = half * 2 + j;
#pragma unroll
                for (int i = 0; i < 4; ++i) {
                    const float s01 = p01[jj][i].x + p01[jj][i].y;
                    const float s23 = p23[jj][i].x + p23[jj][i].y;
                    Ism[(ty + 16 * j) * ISMLD + (tx + 16 * i)] =
                        (s01 + s23) + bsh[tx + 16 * i];    // (l0+l1)+(l2+l3)+b
                }
            }
            __syncthreads();

            // f32 LIF scan over this quarter-chunk; one thread per h.
            if (tid < BN) {
                const size_t srow0 =
                    ((size_t)(bb * T_ + c * BM + half * 32)) * HID_ + h0 + tid;
#pragma unroll 4
                for (int t = 0; t < 32; ++t) {
                    const float It = Ism[t * ISMLD + tid];
                    const float am = ALPHA_F * mem;   // rounded mul
                    mem = am + It;                    // rounded add
                    const bool fire = (mem >= 1.0f);
                    spikes[srow0 + (size_t)t * HID_] = fire ? 1.0f : 0.0f;
                    if (fire) mem = 0.0f;
                }
            }
            __syncthreads();   // scan's Ism reads done before Ism rewrite /
                               // next chunk's iter-0 commit into AB1
        }
    }

    if (tid < BN) memf[(size_t)bb * HID_ + h0 + tid] = mem;
}

extern "C" void kernel_launch(void* const* d_in, const int* in_sizes, int n_in,
                              void* d_out, int out_size, void* d_ws, size_t ws_size,
                              hipStream_t stream) {
    const float* x    = (const float*)d_in[0];   // [B,T,K] f32
    const float* W    = (const float*)d_in[1];   // [H,K] f32
    const float* bias = (const float*)d_in[2];   // [H] f32
    float* out    = (float*)d_out;
    float* spikes = out;                          // [B,T,H]
    float* memf   = out + (size_t)B_ * T_ * HID_; // [B,H]

    dim3 grid(B_, HID_ / BN);   // 64 x 16 = 1024 blocks
    snn_np_wide<<<grid, dim3(256), 0, stream>>>(x, W, bias, spikes, memf);
}

// Round 4
// 3190.157 us; speedup vs baseline: 8.2472x; 8.2472x over previous
//
#include <hip/hip_runtime.h>

// Problem constants
#define B_    64
#define T_    512
#define KDIM  1024
#define HID_  1024

// R16 GEMM geometry: 64x32 tile, 128 threads (2 waves), 4x4/thread, BK=16.
#define BM 64     // t rows per block
#define BN 32     // h cols per block
#define BK 16     // one numpy 16-k block per slice
#define LDA 20    // padded LDS row: 16 + 4 floats (conflict-free: stride 4 banks)
#define NSL 64    // slices per block = KDIM/BK
#define BOFF 1280   // B region offset (64*20 floats)
#define BUFSZ 1920  // per-buffer floats: A 64x20 + B 32x20
// total smem = 2*1920 floats = 15360 B -> 10 blocks/CU by LDS

// f32 correctly rounded from python float math.exp(-1.0/20.0)
#define ALPHA_F 0.95122942450071400909f

typedef float v4f __attribute__((ext_vector_type(4)));
typedef float v2f __attribute__((ext_vector_type(2)));

// Bit-faithful replication of the harness numpy f32 reference: per output
// element 4 f32 accumulator lanes (lane l sums k = l mod 4), 16-k blocks
// ascending (slices ascending), q descending within block, mul/add separately
// rounded (no FMA), hadd tree (l0+l1)+(l2+l3), one f32 bias add (moved to the
// scan kernel, same rounding position), f32 scan. Chain identical to R6..R15.
//
// R16 vs R12 (1.505 ms, VALUBusy 72%): post-mortems killed both alternate
// theories — LDS pipe is light (A-reads broadcast 4 addrs, B-reads 16 addrs
// conflict-free; R13's byte-halving was a no-op) and bigger tiles spill
// (4-lane chain => acc = 4*r*c floats; 8x4 needs ~180 VGPR, R15 wrote 88 GB
// of scratch). Remaining idle = barrier convergence: 4-wave blocks, only 4
// independent barrier domains/CU, serial 64-iter scan stalling 3 waves per
// chunk. R16 decouples: (1) this kernel is a pure GEMM over grid
// (B, T/64, H/32) = 16384 blocks of 128 threads writing I into the spikes
// buffer — 2-wave barrier domains, 8-10 blocks/CU, no Ism/scan/chunk loop;
// (2) snn_scan below does the LIF recurrence in place.
__global__ __launch_bounds__(128, 4) void snn_gemm_np(
    const float* __restrict__ x,     // [B,T,K] f32
    const float* __restrict__ W,     // [H,K] f32
    float* __restrict__ Iout)        // [B,T,H] f32 out (I, no bias)
{
#pragma clang fp contract(off)       // numpy SSE path has no FMA: mul+add only
    __shared__ float smem[2 * BUFSZ];   // 15360 B
    float* const AB0 = smem;            // A @0, B @1280
    float* const AB1 = smem + BUFSZ;

    const int tid = threadIdx.x;
    const int bb  = blockIdx.x;         // batch index
    const int t0  = blockIdx.y * BM;    // t tile origin
    const int h0  = blockIdx.z * BN;    // h tile origin

    const int tx = tid & 7;             // h micro (4 cols, stride 8)
    const int ty = tid >> 3;            // t micro (4 rows, stride 16)

    const int sr = tid >> 2;            // staging row 0..31
    const int sc = (tid & 3) << 2;      // staging col 0,4,8,12

    const float* xb = x + ((size_t)bb * T_ + t0) * KDIM;
    const float* Wb = W + (size_t)h0 * KDIM;

    // ---- prologue: slice 0 -> AB0; slice 1 -> regs ----
    float4 pa0, pa1, pw;
    pa0 = *(const float4*)&xb[(size_t)sr * KDIM + sc];
    pa1 = *(const float4*)&xb[(size_t)(32 + sr) * KDIM + sc];
    pw  = *(const float4*)&Wb[(size_t)sr * KDIM + sc];
    *(float4*)&AB0[sr * LDA + sc]        = pa0;
    *(float4*)&AB0[(32 + sr) * LDA + sc] = pa1;
    *(float4*)&AB0[BOFF + sr * LDA + sc] = pw;
    pa0 = *(const float4*)&xb[(size_t)sr * KDIM + 16 + sc];
    pa1 = *(const float4*)&xb[(size_t)(32 + sr) * KDIM + 16 + sc];
    pw  = *(const float4*)&Wb[(size_t)sr * KDIM + 16 + sc];
    __syncthreads();                    // AB0 visible

    // numpy 4-lane accumulators, lane-paired: p01 = lanes {0,1}, p23 = {2,3}
    v2f p01[4][4], p23[4][4];
#pragma unroll
    for (int j = 0; j < 4; ++j)
#pragma unroll
        for (int i = 0; i < 4; ++i) {
            p01[j][i] = (v2f)(0.0f);
            p23[j][i] = (v2f)(0.0f);
        }

    for (int s = 0; s < NSL; ++s) {
        float* const cb = (s & 1) ? AB1 : AB0;   // compute buffer (slice s)
        float* const nb = (s & 1) ? AB0 : AB1;   // commit target (slice s+1)

        // 1) commit regs (slice s+1) into nb — overlapped with compute;
        //    nb's old readers finished before the previous barrier.
        if (s + 1 < NSL) {
            *(float4*)&nb[sr * LDA + sc]        = pa0;
            *(float4*)&nb[(32 + sr) * LDA + sc] = pa1;
            *(float4*)&nb[BOFF + sr * LDA + sc] = pw;
        }
        // 2) issue slice s+2 loads; a whole compute phase to land.
        if (s + 2 < NSL) {
            const int nk = (s + 2) << 4;
            pa0 = *(const float4*)&xb[(size_t)sr * KDIM + nk + sc];
            pa1 = *(const float4*)&xb[(size_t)(32 + sr) * KDIM + nk + sc];
            pw  = *(const float4*)&Wb[(size_t)sr * KDIM + nk + sc];
        }
        // 3) compute slice s: one numpy 16-k block; q=3..0 —
        // per-lane acc += a[4q+l]*b[4q+l], mul then add: bitwise equal to
        // numpy's chained a0b0+(a1b1+(a2b2+(a3b3+acc)))
#pragma unroll
        for (int q = 3; q >= 0; --q) {
            const int qc = q << 2;
            v2f a01[4], a23[4], b01[4], b23[4];
#pragma unroll
            for (int j = 0; j < 4; ++j) {
                const v4f a = *(const v4f*)&cb[(ty + 16 * j) * LDA + qc];
                a01[j] = a.xy; a23[j] = a.zw;
            }
#pragma unroll
            for (int i = 0; i < 4; ++i) {
                const v4f b = *(const v4f*)&cb[BOFF + (tx + 8 * i) * LDA + qc];
                b01[i] = b.xy; b23[i] = b.zw;
            }
#pragma unroll
            for (int j = 0; j < 4; ++j)
#pragma unroll
                for (int i = 0; i < 4; ++i) {
                    const v2f m01 = a01[j] * b01[i];   // packed rounded muls
                    const v2f m23 = a23[j] * b23[i];
                    p01[j][i] = p01[j][i] + m01;       // packed rounded adds
                    p23[j][i] = p23[j][i] + m23;
                }
        }
        __syncthreads();   // slice s reads done; slice s+1 commit visible
    }

    // epilogue: hadd (l0+l1)+(l2+l3); store I (bias added in scan kernel)
    float* const Ob = Iout + ((size_t)bb * T_ + t0) * HID_ + h0;
#pragma unroll
    for (int j = 0; j < 4; ++j)
#pragma unroll
        for (int i = 0; i < 4; ++i) {
            const float s01 = p01[j][i].x + p01[j][i].y;
            const float s23 = p23[j][i].x + p23[j][i].y;
            Ob[(ty + 16 * j) * HID_ + tx + 8 * i] = s01 + s23;
        }
}

// LIF scan, in place over the spikes buffer (each thread owns one (b,h)
// column: strictly read-then-overwrite within the thread, no cross-thread
// sharing). Bias added here: It = s + b (same rounding position as the fused
// version's (s01+s23)+b), then mem = alpha*mem + It — chain unchanged.
// 16-deep register prefetch hides HBM/L3 latency (loads are independent of
// the mem recurrence); arrays fully unrolled -> static indices, no scratch.
__global__ __launch_bounds__(256, 2) void snn_scan(
    float* __restrict__ IS,          // in: I (no bias) / out: spikes, in place
    const float* __restrict__ bias,  // [H]
    float* __restrict__ memf)        // [B,H] f32 out
{
#pragma clang fp contract(off)       // alpha*mem + It must be mul then add
    const int gid = blockIdx.x * 256 + threadIdx.x;
    const int b = gid >> 10;
    const int h = gid & (HID_ - 1);
    float* col = IS + (size_t)b * T_ * HID_ + h;
    const float bv = bias[h];
    float mem = 0.0f;

    float cur[16], nxt[16];
#pragma unroll
    for (int k = 0; k < 16; ++k) cur[k] = col[(size_t)k * HID_];

    for (int tg = 0; tg < T_; tg += 16) {
        if (tg + 16 < T_) {
#pragma unroll
            for (int k = 0; k < 16; ++k)
                nxt[k] = col[(size_t)(tg + 16 + k) * HID_];
        }
#pragma unroll
        for (int k = 0; k < 16; ++k) {
            const float It = cur[k] + bv;     // rounded bias add
            const float am = ALPHA_F * mem;   // rounded mul
            mem = am + It;                    // rounded add
            const bool fire = (mem >= 1.0f);
            col[(size_t)(tg + k) * HID_] = fire ? 1.0f : 0.0f;
            if (fire) mem = 0.0f;
        }
#pragma unroll
        for (int k = 0; k < 16; ++k) cur[k] = nxt[k];
    }
    memf[(size_t)b * HID_ + h] = mem;
}

extern "C" void kernel_launch(void* const* d_in, const int* in_sizes, int n_in,
                              void* d_out, int out_size, void* d_ws, size_t ws_size,
                              hipStream_t stream) {
    const float* x    = (const float*)d_in[0];   // [B,T,K] f32
    const float* W    = (const float*)d_in[1];   // [H,K] f32
    const float* bias = (const float*)d_in[2];   // [H] f32
    float* out    = (float*)d_out;
    float* spikes = out;                          // [B,T,H]
    float* memf   = out + (size_t)B_ * T_ * HID_; // [B,H]

    dim3 g1(B_, T_ / BM, HID_ / BN);   // 64 x 8 x 32 = 16384 blocks
    snn_gemm_np<<<g1, dim3(128), 0, stream>>>(x, W, spikes);

    snn_scan<<<dim3((B_ * HID_) / 256), dim3(256), 0, stream>>>(
        spikes, bias, memf);
}

// Round 5
// 1578.869 us; speedup vs baseline: 16.6637x; 2.0205x over previous
//
#include <hip/hip_runtime.h>

// Problem constants
#define B_    64
#define T_    512
#define KDIM  1024
#define HID_  1024

// R17 GEMM geometry: 64x32 tile, 128 threads (2 waves), 4x4/thread, BK=16.
#define BM 64     // t rows per block
#define BN 32     // h cols per block
#define BK 16     // one numpy 16-k block per slice
#define LDA 20    // padded LDS row: 16 + 4 floats (conflict-free: stride 4 banks)
#define NSL 64    // slices per block = KDIM/BK
#define BOFF 1280   // B region offset (64*20 floats)
#define BUFSZ 1920  // per-buffer floats: A 64x20 + B 32x20
// total smem = 2*1920 floats = 15360 B -> 10 blocks/CU by LDS

// f32 correctly rounded from python float math.exp(-1.0/20.0)
#define ALPHA_F 0.95122942450071400909f

typedef float v4f __attribute__((ext_vector_type(4)));
typedef float v2f __attribute__((ext_vector_type(2)));

// Bit-faithful replication of the harness numpy f32 reference: per output
// element 4 f32 accumulator lanes (lane l sums k = l mod 4), 16-k blocks
// ascending (slices ascending), q descending within block, mul/add separately
// rounded (no FMA), hadd tree (l0+l1)+(l2+l3), one f32 bias add (in the scan
// kernel, same rounding position), f32 scan. Chain identical to R6..R16
// (R16 PASSED with this exact split: absmax 0.015625).
//
// R17 vs R16 (3.19 ms): R16's only defect was a register-budget miscompile:
// with 2-wave blocks, __launch_bounds__(128,4) produced a 64-VGPR cap
// (compiler treats the min at workgroup granularity: 4 groups/EU = 8
// waves/EU = 512/8), spilling the 64-float accumulator: WRITE_SIZE 8.7 GB of
// scratch vs 0.13 GB output. Session-wide rule: min-waves > 2 always spilled
// (R14 cap102->48spill, R15 cap128<need180, R16 cap64<need88); (., 2) always
// compiled clean (R12 88 VGPR, R13 128). R17 changes ONE thing:
// __launch_bounds__(128, 2) -> cap 256, expect ~88-100 VGPR, no spill,
// occupancy = min(LDS 10 blocks, VGPR 5 waves/SIMD) = 10 blocks/CU of
// independent 2-wave barrier domains. v_pk f32 is 4cy/wave (rate-equal to
// scalar): datapath floor 874 us; R12's extra 420 us was barrier-convergence
// idle, which the 2-wave domains + high block count attack.
__global__ __launch_bounds__(128, 2) void snn_gemm_np(
    const float* __restrict__ x,     // [B,T,K] f32
    const float* __restrict__ W,     // [H,K] f32
    float* __restrict__ Iout)        // [B,T,H] f32 out (I, no bias)
{
#pragma clang fp contract(off)       // numpy SSE path has no FMA: mul+add only
    __shared__ float smem[2 * BUFSZ];   // 15360 B
    float* const AB0 = smem;            // A @0, B @1280
    float* const AB1 = smem + BUFSZ;

    const int tid = threadIdx.x;
    const int bb  = blockIdx.x;         // batch index
    const int t0  = blockIdx.y * BM;    // t tile origin
    const int h0  = blockIdx.z * BN;    // h tile origin

    const int tx = tid & 7;             // h micro (4 cols, stride 8)
    const int ty = tid >> 3;            // t micro (4 rows, stride 16)

    const int sr = tid >> 2;            // staging row 0..31
    const int sc = (tid & 3) << 2;      // staging col 0,4,8,12

    const float* xb = x + ((size_t)bb * T_ + t0) * KDIM;
    const float* Wb = W + (size_t)h0 * KDIM;

    // ---- prologue: slice 0 -> AB0; slice 1 -> regs ----
    float4 pa0, pa1, pw;
    pa0 = *(const float4*)&xb[(size_t)sr * KDIM + sc];
    pa1 = *(const float4*)&xb[(size_t)(32 + sr) * KDIM + sc];
    pw  = *(const float4*)&Wb[(size_t)sr * KDIM + sc];
    *(float4*)&AB0[sr * LDA + sc]        = pa0;
    *(float4*)&AB0[(32 + sr) * LDA + sc] = pa1;
    *(float4*)&AB0[BOFF + sr * LDA + sc] = pw;
    pa0 = *(const float4*)&xb[(size_t)sr * KDIM + 16 + sc];
    pa1 = *(const float4*)&xb[(size_t)(32 + sr) * KDIM + 16 + sc];
    pw  = *(const float4*)&Wb[(size_t)sr * KDIM + 16 + sc];
    __syncthreads();                    // AB0 visible

    // numpy 4-lane accumulators, lane-paired: p01 = lanes {0,1}, p23 = {2,3}
    v2f p01[4][4], p23[4][4];
#pragma unroll
    for (int j = 0; j < 4; ++j)
#pragma unroll
        for (int i = 0; i < 4; ++i) {
            p01[j][i] = (v2f)(0.0f);
            p23[j][i] = (v2f)(0.0f);
        }

    for (int s = 0; s < NSL; ++s) {
        float* const cb = (s & 1) ? AB1 : AB0;   // compute buffer (slice s)
        float* const nb = (s & 1) ? AB0 : AB1;   // commit target (slice s+1)

        // 1) commit regs (slice s+1) into nb — overlapped with compute;
        //    nb's old readers finished before the previous barrier.
        if (s + 1 < NSL) {
            *(float4*)&nb[sr * LDA + sc]        = pa0;
            *(float4*)&nb[(32 + sr) * LDA + sc] = pa1;
            *(float4*)&nb[BOFF + sr * LDA + sc] = pw;
        }
        // 2) issue slice s+2 loads; a whole compute phase to land.
        if (s + 2 < NSL) {
            const int nk = (s + 2) << 4;
            pa0 = *(const float4*)&xb[(size_t)sr * KDIM + nk + sc];
            pa1 = *(const float4*)&xb[(size_t)(32 + sr) * KDIM + nk + sc];
            pw  = *(const float4*)&Wb[(size_t)sr * KDIM + nk + sc];
        }
        // 3) compute slice s: one numpy 16-k block; q=3..0 —
        // per-lane acc += a[4q+l]*b[4q+l], mul then add: bitwise equal to
        // numpy's chained a0b0+(a1b1+(a2b2+(a3b3+acc)))
#pragma unroll
        for (int q = 3; q >= 0; --q) {
            const int qc = q << 2;
            v2f a01[4], a23[4], b01[4], b23[4];
#pragma unroll
            for (int j = 0; j < 4; ++j) {
                const v4f a = *(const v4f*)&cb[(ty + 16 * j) * LDA + qc];
                a01[j] = a.xy; a23[j] = a.zw;
            }
#pragma unroll
            for (int i = 0; i < 4; ++i) {
                const v4f b = *(const v4f*)&cb[BOFF + (tx + 8 * i) * LDA + qc];
                b01[i] = b.xy; b23[i] = b.zw;
            }
#pragma unroll
            for (int j = 0; j < 4; ++j)
#pragma unroll
                for (int i = 0; i < 4; ++i) {
                    const v2f m01 = a01[j] * b01[i];   // packed rounded muls
                    const v2f m23 = a23[j] * b23[i];
                    p01[j][i] = p01[j][i] + m01;       // packed rounded adds
                    p23[j][i] = p23[j][i] + m23;
                }
        }
        __syncthreads();   // slice s reads done; slice s+1 commit visible
    }

    // epilogue: hadd (l0+l1)+(l2+l3); store I (bias added in scan kernel)
    float* const Ob = Iout + ((size_t)bb * T_ + t0) * HID_ + h0;
#pragma unroll
    for (int j = 0; j < 4; ++j)
#pragma unroll
        for (int i = 0; i < 4; ++i) {
            const float s01 = p01[j][i].x + p01[j][i].y;
            const float s23 = p23[j][i].x + p23[j][i].y;
            Ob[(ty + 16 * j) * HID_ + tx + 8 * i] = s01 + s23;
        }
}

// LIF scan, in place over the spikes buffer (each thread owns one (b,h)
// column: strictly read-then-overwrite within the thread, no cross-thread
// sharing). Bias added here: It = s + b (same rounding position as the fused
// version's (s01+s23)+b), then mem = alpha*mem + It — chain unchanged.
// 16-deep register prefetch hides HBM/L3 latency (loads are independent of
// the mem recurrence); arrays fully unrolled -> static indices, no scratch.
__global__ __launch_bounds__(256, 2) void snn_scan(
    float* __restrict__ IS,          // in: I (no bias) / out: spikes, in place
    const float* __restrict__ bias,  // [H]
    float* __restrict__ memf)        // [B,H] f32 out
{
#pragma clang fp contract(off)       // alpha*mem + It must be mul then add
    const int gid = blockIdx.x * 256 + threadIdx.x;
    const int b = gid >> 10;
    const int h = gid & (HID_ - 1);
    float* col = IS + (size_t)b * T_ * HID_ + h;
    const float bv = bias[h];
    float mem = 0.0f;

    float cur[16], nxt[16];
#pragma unroll
    for (int k = 0; k < 16; ++k) cur[k] = col[(size_t)k * HID_];

    for (int tg = 0; tg < T_; tg += 16) {
        if (tg + 16 < T_) {
#pragma unroll
            for (int k = 0; k < 16; ++k)
                nxt[k] = col[(size_t)(tg + 16 + k) * HID_];
        }
#pragma unroll
        for (int k = 0; k < 16; ++k) {
            const float It = cur[k] + bv;     // rounded bias add
            const float am = ALPHA_F * mem;   // rounded mul
            mem = am + It;                    // rounded add
            const bool fire = (mem >= 1.0f);
            col[(size_t)(tg + k) * HID_] = fire ? 1.0f : 0.0f;
            if (fire) mem = 0.0f;
        }
#pragma unroll
        for (int k = 0; k < 16; ++k) cur[k] = nxt[k];
    }
    memf[(size_t)b * HID_ + h] = mem;
}

extern "C" void kernel_launch(void* const* d_in, const int* in_sizes, int n_in,
                              void* d_out, int out_size, void* d_ws, size_t ws_size,
                              hipStream_t stream) {
    const float* x    = (const float*)d_in[0];   // [B,T,K] f32
    const float* W    = (const float*)d_in[1];   // [H,K] f32
    const float* bias = (const float*)d_in[2];   // [H] f32
    float* out    = (float*)d_out;
    float* spikes = out;                          // [B,T,H]
    float* memf   = out + (size_t)B_ * T_ * HID_; // [B,H]

    dim3 g1(B_, T_ / BM, HID_ / BN);   // 64 x 8 x 32 = 16384 blocks
    snn_gemm_np<<<g1, dim3(128), 0, stream>>>(x, W, spikes);

    snn_scan<<<dim3((B_ * HID_) / 256), dim3(256), 0, stream>>>(
        spikes, bias, memf);
}